// Round 3
// baseline (1328.547 us; speedup 1.0000x reference)
//
#include <hip/hip_runtime.h>
#include <hip/hip_bf16.h>

#define B_TOK 65536
#define HDIM  1024
#define EXP   16
#define IDIM  1024

typedef __attribute__((ext_vector_type(8))) short bf16x8_t;   // 8 bf16 (4 VGPRs)
typedef __attribute__((ext_vector_type(4))) float f32x4_t;    // 4 fp32 (native vec)

// ---- helpers ---------------------------------------------------------------

__device__ __forceinline__ unsigned short f2bf(float f) {
    unsigned int u = __float_as_uint(f);
    unsigned int r = (u + 0x7FFFu + ((u >> 16) & 1u)) >> 16;   // RNE
    return (unsigned short)r;
}

__device__ __forceinline__ void async_load16(const void* g, void* l) {
    __builtin_amdgcn_global_load_lds(
        (const __attribute__((address_space(1))) unsigned int*)g,
        (__attribute__((address_space(3))) unsigned int*)l,
        16, 0, 0);
}

// ---- kernel 1: prep = gate (+token-list append) | We f32->bf16 -------------
// Blocks [0,1024): gate. fp32 math and reduction order BIT-IDENTICAL to the
// passing round-2 kernel (argmax near-ties: bf16 scores would misroute ~100s
// of tokens; fp32 is required). New: lane-0 atomicAdd append to token_list
// (order within an expert is irrelevant). cnts zeroed by hipMemsetAsync.
// Blocks [1024,1536): We conversion, grid-stride.
__global__ __launch_bounds__(256) void prep_kernel(
    const float* __restrict__ x, const float* __restrict__ Wg,
    const float* __restrict__ we,
    unsigned short* __restrict__ xbf, unsigned short* __restrict__ webf,
    int* __restrict__ token_list, int* __restrict__ cnts)
{
    const int tid = threadIdx.x;

    if (blockIdx.x >= 1024) {               // ---- We f32 -> bf16 ----
        const size_t n4 = (size_t)EXP * IDIM * HDIM / 4;   // 4194304
        const size_t stride = (size_t)512 * 256;
        for (size_t i = (size_t)(blockIdx.x - 1024) * 256 + tid; i < n4; i += stride) {
            f32x4_t v = __builtin_nontemporal_load((const f32x4_t*)we + i);
            ushort4 o;
            o.x = f2bf(v[0]); o.y = f2bf(v[1]); o.z = f2bf(v[2]); o.w = f2bf(v[3]);
            ((ushort4*)webf)[i] = o;
        }
        return;
    }

    // ---- gate ----
    __shared__ float wg[EXP * HDIM];          // 64 KB
    { // cooperative Wg load, coalesced float4
        const f32x4_t* s = (const f32x4_t*)Wg;
        f32x4_t* d = (f32x4_t*)wg;
        for (int i = tid; i < EXP * HDIM / 4; i += 256) d[i] = s[i];
    }
    __syncthreads();

    const int wid = tid >> 6, lane = tid & 63;
    const int gw = blockIdx.x * 4 + wid;      // 4096 waves

    for (int it = 0; it < 4; ++it) {
        const int t0 = gw * 16 + it * 4;
        f32x4_t xv[4][4];
        float acc[4][EXP];
        #pragma unroll
        for (int t = 0; t < 4; ++t) {
            const f32x4_t* row = (const f32x4_t*)(x + (size_t)(t0 + t) * HDIM);
            #pragma unroll
            for (int j = 0; j < 4; ++j)
                xv[t][j] = __builtin_nontemporal_load(row + j * 64 + lane);
        }
        #pragma unroll
        for (int t = 0; t < 4; ++t)
            #pragma unroll
            for (int e = 0; e < EXP; ++e) acc[t][e] = 0.f;

        #pragma unroll
        for (int j = 0; j < 4; ++j) {
            #pragma unroll
            for (int e = 0; e < EXP; ++e) {
                f32x4_t wv = *(const f32x4_t*)(wg + e * HDIM + j * 256 + lane * 4);
                #pragma unroll
                for (int t = 0; t < 4; ++t) {
                    acc[t][e] += xv[t][j][0] * wv[0] + xv[t][j][1] * wv[1]
                               + xv[t][j][2] * wv[2] + xv[t][j][3] * wv[3];
                }
            }
        }
        // bf16 store of x (coalesced: lanes write contiguous 8B)
        #pragma unroll
        for (int t = 0; t < 4; ++t) {
            unsigned short* orow = xbf + (size_t)(t0 + t) * HDIM;
            #pragma unroll
            for (int j = 0; j < 4; ++j) {
                ushort4 o;
                o.x = f2bf(xv[t][j][0]); o.y = f2bf(xv[t][j][1]);
                o.z = f2bf(xv[t][j][2]); o.w = f2bf(xv[t][j][3]);
                *(ushort4*)(orow + j * 256 + lane * 4) = o;
            }
        }
        // reduce + argmax (first-max-wins == np.argmax); in-place on acc
        #pragma unroll
        for (int t = 0; t < 4; ++t) {
            #pragma unroll
            for (int d = 32; d >= 1; d >>= 1) {
                #pragma unroll
                for (int e = 0; e < EXP; ++e)
                    acc[t][e] += __shfl_xor(acc[t][e], d, 64);
            }
            int best = 0; float bv = acc[t][0];
            #pragma unroll
            for (int e = 1; e < EXP; ++e)
                if (acc[t][e] > bv) { bv = acc[t][e]; best = e; }
            if (lane == 0) {
                const int pos = atomicAdd(&cnts[best], 1);   // device-scope
                token_list[(size_t)best * B_TOK + pos] = t0 + t;
            }
        }
    }
}

// ---- kernel 2: grouped GEMM, 3-buffer counted-vmcnt pipeline ---------------
// BM=128 (gathered tokens), BN=256, BK=64. 512 threads = 8 waves (2M x 4N),
// wave tile 64x64 (M_rep=N_rep=4). LDS: 3 sides x (A 16KB + B 32KB) = 144 KB.
// Pipeline invariant (L=6 global_load_lds per tile per thread):
//   entering iter t: <=6 outstanding (tile t+1's). Iter t: stage tile t+2
//   (+6 -> <=12), compute buf[t%3], s_waitcnt vmcnt(6) -> tile t+1 retired
//   (landed in LDS), raw s_barrier -> visible to all waves. Never vmcnt(0)
//   in the main loop (T4). Buf (t+2)%3 was computed in iter t-1, barrier-
//   protected. sched_barrier(0) after each barrier (rule 18: stop ds_read
//   hoisting above the barrier). T5 setprio around MFMA cluster.
// T2 swizzle unchanged (seg ^ (row&7) on both global source and LDS read;
// LDS dest linear) -- measured 0 bank conflicts in round 2.
__global__ __launch_bounds__(512, 2) void moe_gemm(
    const unsigned short* __restrict__ xbf,
    const unsigned short* __restrict__ webf,
    const int* __restrict__ token_list,
    const int* __restrict__ counts,
    float* __restrict__ out)
{
    // grid = (4 n) x (48 m) x (16 e) = 3072 blocks; m-cap 48*128 = 6144/expert
    // (counts ~ Binomial(65536,1/16): mean 4096, sigma 62 -> 33-sigma margin).
    // XCD chunking (3072 % 8 == 0, bijective), m-tile fastest within a chunk:
    const int lin = blockIdx.x + 4 * (blockIdx.y + 48 * (int)blockIdx.z);
    const int logical = (lin & 7) * 384 + (lin >> 3);
    const int mt = logical % 48;
    const int nt = (logical / 48) & 3;
    const int e  = logical / 192;

    const int cnt = counts[e];
    const int m0 = mt * 128;
    if (m0 >= cnt) return;
    const int row_count = min(128, cnt - m0);
    const int n0 = nt * 256;

    // side s: A at lds + s*24576 (8192 shorts), B at +8192 (16384 shorts)
    __shared__ unsigned short lds[3 * 24576];   // 144 KB

    const int tid = threadIdx.x;
    const int wid = tid >> 6, lane = tid & 63;
    const int lrow = lane >> 3;                  // 0..7: row sub-index
    const int ksw  = (lane & 7) ^ lrow;          // swizzled 16B segment

    const int* tl = token_list + (size_t)e * B_TOK + m0;
    size_t abase[2], bbase[4];
    #pragma unroll
    for (int j = 0; j < 2; ++j) {                // A rows: j*64 + wid*8 + lrow
        const int r = j * 64 + wid * 8 + lrow;
        const int tok = tl[min(r, row_count - 1)];
        abase[j] = ((size_t)tok * HDIM + ksw * 8) * 2;
    }
    #pragma unroll
    for (int j = 0; j < 4; ++j) {                // B rows: j*64 + wid*8 + lrow
        const int r = j * 64 + wid * 8 + lrow;
        bbase[j] = (((size_t)e * IDIM + n0 + r) * HDIM + ksw * 8) * 2;
    }
    const char* xg = (const char*)xbf;
    const char* wp = (const char*)webf;

    f32x4_t acc[4][4];
    const f32x4_t z = {0.f, 0.f, 0.f, 0.f};
    #pragma unroll
    for (int mi = 0; mi < 4; ++mi)
        #pragma unroll
        for (int ni = 0; ni < 4; ++ni) acc[mi][ni] = z;

    const int wm = wid >> 2, wn = wid & 3;       // 2 x 4 waves
    const int quad = lane >> 4, l16 = lane & 15;
    const int rx = l16 & 7;                      // row&7 for all frag rows
    const int s0 = (quad ^ rx) << 3;             // swizzled read seg, kk=0
    const int s1 = ((quad + 4) ^ rx) << 3;       // swizzled read seg, kk=32
    const int arow0 = (wm * 64 + l16) * 64;      // shorts
    const int brow0 = (wn * 64 + l16) * 64;

#define LDSA(S) (lds + (S) * 24576)
#define LDSB(S) (lds + (S) * 24576 + 8192)

#define STAGE(S, T)                                                            \
    { _Pragma("unroll")                                                        \
      for (int j = 0; j < 2; ++j)                                              \
        async_load16(xg + abase[j] + (size_t)(T) * 128,                        \
                     (char*)LDSA(S) + (j * 512 + wid * 64 + lane) * 16);       \
      _Pragma("unroll")                                                        \
      for (int j = 0; j < 4; ++j)                                              \
        async_load16(wp + bbase[j] + (size_t)(T) * 128,                        \
                     (char*)LDSB(S) + (j * 512 + wid * 64 + lane) * 16);       \
    }

#define COMPUTE(S)                                                             \
    { _Pragma("unroll")                                                        \
      for (int kkh = 0; kkh < 2; ++kkh) {                                      \
        const int co = kkh ? s1 : s0;                                          \
        bf16x8_t av[4], bv[4];                                                 \
        _Pragma("unroll")                                                      \
        for (int mi = 0; mi < 4; ++mi)                                         \
            av[mi] = *(const bf16x8_t*)(LDSA(S) + arow0 + mi * 1024 + co);     \
        _Pragma("unroll")                                                      \
        for (int ni = 0; ni < 4; ++ni)                                         \
            bv[ni] = *(const bf16x8_t*)(LDSB(S) + brow0 + ni * 1024 + co);     \
        _Pragma("unroll")                                                      \
        for (int mi = 0; mi < 4; ++mi)                                         \
            _Pragma("unroll")                                                  \
            for (int ni = 0; ni < 4; ++ni)                                     \
                acc[mi][ni] = __builtin_amdgcn_mfma_f32_16x16x32_bf16(         \
                    av[mi], bv[ni], acc[mi][ni], 0, 0, 0);                     \
      } }

    // prologue: stage tiles 0,1; wait tile 0 (6 of tile 1 may fly)
    STAGE(0, 0)
    STAGE(1, 1)
    asm volatile("s_waitcnt vmcnt(6)" ::: "memory");
    __builtin_amdgcn_s_barrier();
    __builtin_amdgcn_sched_barrier(0);

    #pragma unroll
    for (int t = 0; t < 16; ++t) {
        const int s = t % 3;
        if (t + 2 < 16) {
            const int s2 = (t + 2) % 3;          // computed in iter t-1: free
            STAGE(s2, t + 2)
        }
        __builtin_amdgcn_s_setprio(1);
        COMPUTE(s)
        __builtin_amdgcn_s_setprio(0);
        if (t + 2 < 16) {
            asm volatile("s_waitcnt vmcnt(6)" ::: "memory");   // tile t+1 landed
        } else if (t + 1 < 16) {
            asm volatile("s_waitcnt vmcnt(0)" ::: "memory");   // drain last tile
        }
        if (t + 1 < 16) {
            __builtin_amdgcn_s_barrier();
            __builtin_amdgcn_sched_barrier(0);
        }
    }

    // epilogue: C/D layout col = lane&15, row = (lane>>4)*4 + reg
    #pragma unroll
    for (int mi = 0; mi < 4; ++mi) {
        const int rl0 = wm * 64 + mi * 16 + quad * 4;
        #pragma unroll
        for (int r = 0; r < 4; ++r) {
            const int rl = rl0 + r;
            if (rl < row_count) {
                const int tok = tl[rl];
                float* orow = out + (size_t)tok * IDIM + n0 + wn * 64 + l16;
                #pragma unroll
                for (int ni = 0; ni < 4; ++ni)
                    __builtin_nontemporal_store(acc[mi][ni][r], orow + ni * 16);
            }
        }
    }
#undef STAGE
#undef COMPUTE
#undef LDSA
#undef LDSB
}

// ---- launcher --------------------------------------------------------------
extern "C" void kernel_launch(void* const* d_in, const int* in_sizes, int n_in,
                              void* d_out, int out_size, void* d_ws, size_t ws_size,
                              hipStream_t stream) {
    const float* x  = (const float*)d_in[0];
    const float* Wg = (const float*)d_in[1];
    const float* We = (const float*)d_in[2];
    float* out = (float*)d_out;

    char* ws = (char*)d_ws;
    // ws layout (bytes):
    //   [0, 128 MiB)   x_bf16     [65536][1024]
    //   [+,  32 MiB)   we_bf16    [16][1024][1024]
    //   [+,   4 MiB)   token_list [16][65536] int
    //   [+,   64 B )   counts     [16] int
    unsigned short* xbf   = (unsigned short*)(ws);
    unsigned short* webf  = (unsigned short*)(ws + 134217728);
    int*            tlist = (int*)(ws + 167772160);
    int*            cnts  = (int*)(ws + 171966464);

    hipMemsetAsync(cnts, 0, EXP * sizeof(int), stream);
    prep_kernel<<<1536, 256, 0, stream>>>(x, Wg, We, xbf, webf, tlist, cnts);
    moe_gemm<<<dim3(4, 48, 16), 512, 0, stream>>>(xbf, webf, tlist, cnts, out);
}

// Round 4
// 936.522 us; speedup vs baseline: 1.4186x; 1.4186x over previous
//
#include <hip/hip_runtime.h>
#include <hip/hip_bf16.h>

#define B_TOK 65536
#define HDIM  1024
#define EXP   16
#define IDIM  1024

typedef __attribute__((ext_vector_type(8))) short bf16x8_t;   // 8 bf16 (4 VGPRs)
typedef __attribute__((ext_vector_type(4))) float f32x4_t;    // 4 fp32 (native vec)

// ---- helpers ---------------------------------------------------------------

__device__ __forceinline__ unsigned short f2bf(float f) {
    unsigned int u = __float_as_uint(f);
    unsigned int r = (u + 0x7FFFu + ((u >> 16) & 1u)) >> 16;   // RNE
    return (unsigned short)r;
}

__device__ __forceinline__ void async_load16(const void* g, void* l) {
    __builtin_amdgcn_global_load_lds(
        (const __attribute__((address_space(1))) unsigned int*)g,
        (__attribute__((address_space(3))) unsigned int*)l,
        16, 0, 0);
}

// ---- kernel 1: gate (scores + argmax) fused with x f32->bf16 ---------------
// Round-4 redesign: NO LDS (Wg 64KB is read-only -> L1/L2 cache it), NO
// atomics (plain eidx store; scatter kernel rebuilds lists). 2 tokens/wave
// register blocking (~90 VGPR -> ~5 waves/SIMD vs round-2's 2). Per-token FP
// summation order, lane mapping, butterfly reduce and argmax scan are
// operand-identical to the passing round-2 kernel (routing must not shift).
__global__ __launch_bounds__(256) void gate_kernel(
    const float* __restrict__ x, const float* __restrict__ Wg,
    unsigned short* __restrict__ xbf, int* __restrict__ eidx)
{
    const int tid = threadIdx.x;
    const int wid = tid >> 6, lane = tid & 63;
    const int gw = blockIdx.x * 4 + wid;      // 8192 waves, 8 tokens each

    #pragma unroll 1
    for (int it = 0; it < 4; ++it) {
        const int t0 = gw * 8 + it * 2;
        f32x4_t xv[2][4];
        float acc[2][EXP];
        #pragma unroll
        for (int t = 0; t < 2; ++t) {
            const f32x4_t* row = (const f32x4_t*)(x + (size_t)(t0 + t) * HDIM);
            #pragma unroll
            for (int j = 0; j < 4; ++j)
                xv[t][j] = __builtin_nontemporal_load(row + j * 64 + lane);
        }
        #pragma unroll
        for (int t = 0; t < 2; ++t)
            #pragma unroll
            for (int e = 0; e < EXP; ++e) acc[t][e] = 0.f;

        #pragma unroll
        for (int j = 0; j < 4; ++j) {
            #pragma unroll
            for (int e = 0; e < EXP; ++e) {
                f32x4_t wv = *(const f32x4_t*)(Wg + e * HDIM + j * 256 + lane * 4);
                #pragma unroll
                for (int t = 0; t < 2; ++t) {
                    acc[t][e] += xv[t][j][0] * wv[0] + xv[t][j][1] * wv[1]
                               + xv[t][j][2] * wv[2] + xv[t][j][3] * wv[3];
                }
            }
        }
        // bf16 store of x (coalesced: lanes write contiguous 8B)
        #pragma unroll
        for (int t = 0; t < 2; ++t) {
            unsigned short* orow = xbf + (size_t)(t0 + t) * HDIM;
            #pragma unroll
            for (int j = 0; j < 4; ++j) {
                ushort4 o;
                o.x = f2bf(xv[t][j][0]); o.y = f2bf(xv[t][j][1]);
                o.z = f2bf(xv[t][j][2]); o.w = f2bf(xv[t][j][3]);
                *(ushort4*)(orow + j * 256 + lane * 4) = o;
            }
        }
        // reduce + argmax (first-max-wins == np.argmax); in-place on acc
        #pragma unroll
        for (int t = 0; t < 2; ++t) {
            #pragma unroll
            for (int d = 32; d >= 1; d >>= 1) {
                #pragma unroll
                for (int e = 0; e < EXP; ++e)
                    acc[t][e] += __shfl_xor(acc[t][e], d, 64);
            }
            int best = 0; float bv = acc[t][0];
            #pragma unroll
            for (int e = 1; e < EXP; ++e)
                if (acc[t][e] > bv) { bv = acc[t][e]; best = e; }
            if (lane == 0) eidx[t0 + t] = best;
        }
    }
}

// ---- kernel 2: We f32 -> bf16 (nontemporal fp32 loads: read-once) ----------
__global__ __launch_bounds__(256) void convert_we(
    const float* __restrict__ we, unsigned short* __restrict__ webf)
{
    const size_t n4 = (size_t)EXP * IDIM * HDIM / 4;
    const size_t stride = (size_t)gridDim.x * 256;
    for (size_t i = (size_t)blockIdx.x * 256 + threadIdx.x; i < n4; i += stride) {
        f32x4_t v = __builtin_nontemporal_load((const f32x4_t*)we + i);
        ushort4 o;
        o.x = f2bf(v[0]); o.y = f2bf(v[1]); o.z = f2bf(v[2]); o.w = f2bf(v[3]);
        ((ushort4*)webf)[i] = o;
    }
}

// ---- kernel 3: parallel token-list build (round-2 proven) -------------------
// 1024 waves, one token/thread. Per-wave ballot aggregation -> one atomicAdd
// per (wave, expert). Order within an expert's list is irrelevant.
__global__ __launch_bounds__(256) void scatter_kernel(
    const int* __restrict__ eidx, int* __restrict__ token_list,
    int* __restrict__ counts)
{
    const int b = blockIdx.x * 256 + threadIdx.x;
    const int lane = threadIdx.x & 63;
    const int e = eidx[b];
    unsigned long long mymask = 0;
    int baseval = 0;
    #pragma unroll
    for (int ex = 0; ex < EXP; ++ex) {
        unsigned long long m = __ballot(e == ex);
        if (e == ex) mymask = m;
        int c = __popcll(m);
        if (lane == ex && c) baseval = atomicAdd(&counts[ex], c);
    }
    const int base = __shfl(baseval, e, 64);
    const int pos = base + __popcll(mymask & ((1ull << lane) - 1ull));
    token_list[(size_t)e * B_TOK + pos] = b;
}

// ---- kernel 4: grouped GEMM, 3-buffer counted-vmcnt pipeline ---------------
// UNCHANGED from round 3 (this round's profile finally measures it).
// BM=128 (gathered tokens), BN=256, BK=64. 512 threads = 8 waves (2M x 4N),
// wave tile 64x64. LDS: 3 sides x (A 16KB + B 32KB) = 144 KB.
// Pipeline invariant (L=6 global_load_lds per tile per thread):
//   entering iter t: <=6 outstanding (tile t+1's). Iter t: stage tile t+2
//   (+6 -> <=12), compute buf[t%3], s_waitcnt vmcnt(6) -> tile t+1 retired,
//   raw s_barrier. Never vmcnt(0) in the main loop (T4). sched_barrier(0)
//   after each barrier (rule 18). T5 setprio around MFMA cluster.
__global__ __launch_bounds__(512, 2) void moe_gemm(
    const unsigned short* __restrict__ xbf,
    const unsigned short* __restrict__ webf,
    const int* __restrict__ token_list,
    const int* __restrict__ counts,
    float* __restrict__ out)
{
    const int lin = blockIdx.x + 4 * (blockIdx.y + 48 * (int)blockIdx.z);
    const int logical = (lin & 7) * 384 + (lin >> 3);
    const int mt = logical % 48;
    const int nt = (logical / 48) & 3;
    const int e  = logical / 192;

    const int cnt = counts[e];
    const int m0 = mt * 128;
    if (m0 >= cnt) return;
    const int row_count = min(128, cnt - m0);
    const int n0 = nt * 256;

    __shared__ unsigned short lds[3 * 24576];   // 144 KB

    const int tid = threadIdx.x;
    const int wid = tid >> 6, lane = tid & 63;
    const int lrow = lane >> 3;                  // 0..7: row sub-index
    const int ksw  = (lane & 7) ^ lrow;          // swizzled 16B segment

    const int* tl = token_list + (size_t)e * B_TOK + m0;
    size_t abase[2], bbase[4];
    #pragma unroll
    for (int j = 0; j < 2; ++j) {
        const int r = j * 64 + wid * 8 + lrow;
        const int tok = tl[min(r, row_count - 1)];
        abase[j] = ((size_t)tok * HDIM + ksw * 8) * 2;
    }
    #pragma unroll
    for (int j = 0; j < 4; ++j) {
        const int r = j * 64 + wid * 8 + lrow;
        bbase[j] = (((size_t)e * IDIM + n0 + r) * HDIM + ksw * 8) * 2;
    }
    const char* xg = (const char*)xbf;
    const char* wp = (const char*)webf;

    f32x4_t acc[4][4];
    const f32x4_t z = {0.f, 0.f, 0.f, 0.f};
    #pragma unroll
    for (int mi = 0; mi < 4; ++mi)
        #pragma unroll
        for (int ni = 0; ni < 4; ++ni) acc[mi][ni] = z;

    const int wm = wid >> 2, wn = wid & 3;       // 2 x 4 waves
    const int quad = lane >> 4, l16 = lane & 15;
    const int rx = l16 & 7;
    const int s0 = (quad ^ rx) << 3;
    const int s1 = ((quad + 4) ^ rx) << 3;
    const int arow0 = (wm * 64 + l16) * 64;
    const int brow0 = (wn * 64 + l16) * 64;

#define LDSA(S) (lds + (S) * 24576)
#define LDSB(S) (lds + (S) * 24576 + 8192)

#define STAGE(S, T)                                                            \
    { _Pragma("unroll")                                                        \
      for (int j = 0; j < 2; ++j)                                              \
        async_load16(xg + abase[j] + (size_t)(T) * 128,                        \
                     (char*)LDSA(S) + (j * 512 + wid * 64 + lane) * 16);       \
      _Pragma("unroll")                                                        \
      for (int j = 0; j < 4; ++j)                                              \
        async_load16(wp + bbase[j] + (size_t)(T) * 128,                        \
                     (char*)LDSB(S) + (j * 512 + wid * 64 + lane) * 16);       \
    }

#define COMPUTE(S)                                                             \
    { _Pragma("unroll")                                                        \
      for (int kkh = 0; kkh < 2; ++kkh) {                                      \
        const int co = kkh ? s1 : s0;                                          \
        bf16x8_t av[4], bv[4];                                                 \
        _Pragma("unroll")                                                      \
        for (int mi = 0; mi < 4; ++mi)                                         \
            av[mi] = *(const bf16x8_t*)(LDSA(S) + arow0 + mi * 1024 + co);     \
        _Pragma("unroll")                                                      \
        for (int ni = 0; ni < 4; ++ni)                                         \
            bv[ni] = *(const bf16x8_t*)(LDSB(S) + brow0 + ni * 1024 + co);     \
        _Pragma("unroll")                                                      \
        for (int mi = 0; mi < 4; ++mi)                                         \
            _Pragma("unroll")                                                  \
            for (int ni = 0; ni < 4; ++ni)                                     \
                acc[mi][ni] = __builtin_amdgcn_mfma_f32_16x16x32_bf16(         \
                    av[mi], bv[ni], acc[mi][ni], 0, 0, 0);                     \
      } }

    STAGE(0, 0)
    STAGE(1, 1)
    asm volatile("s_waitcnt vmcnt(6)" ::: "memory");
    __builtin_amdgcn_s_barrier();
    __builtin_amdgcn_sched_barrier(0);

    #pragma unroll
    for (int t = 0; t < 16; ++t) {
        const int s = t % 3;
        if (t + 2 < 16) {
            const int s2 = (t + 2) % 3;
            STAGE(s2, t + 2)
        }
        __builtin_amdgcn_s_setprio(1);
        COMPUTE(s)
        __builtin_amdgcn_s_setprio(0);
        if (t + 2 < 16) {
            asm volatile("s_waitcnt vmcnt(6)" ::: "memory");
        } else if (t + 1 < 16) {
            asm volatile("s_waitcnt vmcnt(0)" ::: "memory");
        }
        if (t + 1 < 16) {
            __builtin_amdgcn_s_barrier();
            __builtin_amdgcn_sched_barrier(0);
        }
    }

    // epilogue: C/D layout col = lane&15, row = (lane>>4)*4 + reg
    #pragma unroll
    for (int mi = 0; mi < 4; ++mi) {
        const int rl0 = wm * 64 + mi * 16 + quad * 4;
        #pragma unroll
        for (int r = 0; r < 4; ++r) {
            const int rl = rl0 + r;
            if (rl < row_count) {
                const int tok = tl[rl];
                float* orow = out + (size_t)tok * IDIM + n0 + wn * 64 + l16;
                #pragma unroll
                for (int ni = 0; ni < 4; ++ni)
                    __builtin_nontemporal_store(acc[mi][ni][r], orow + ni * 16);
            }
        }
    }
#undef STAGE
#undef COMPUTE
#undef LDSA
#undef LDSB
}

// ---- launcher --------------------------------------------------------------
extern "C" void kernel_launch(void* const* d_in, const int* in_sizes, int n_in,
                              void* d_out, int out_size, void* d_ws, size_t ws_size,
                              hipStream_t stream) {
    const float* x  = (const float*)d_in[0];
    const float* Wg = (const float*)d_in[1];
    const float* We = (const float*)d_in[2];
    float* out = (float*)d_out;

    char* ws = (char*)d_ws;
    // ws layout (bytes):
    //   [0, 128 MiB)   x_bf16     [65536][1024]
    //   [+,  32 MiB)   we_bf16    [16][1024][1024]
    //   [+, 256 KiB)   eidx       [65536] int
    //   [+,  64 B  )   counts     [16] int
    //   [+,   4 MiB)   token_list [16][65536] int
    unsigned short* xbf   = (unsigned short*)(ws);
    unsigned short* webf  = (unsigned short*)(ws + 134217728);
    int*            eidx  = (int*)(ws + 167772160);
    int*            cnts  = (int*)(ws + 168034304);
    int*            tlist = (int*)(ws + 168034560);

    hipMemsetAsync(cnts, 0, EXP * sizeof(int), stream);
    gate_kernel<<<2048, 256, 0, stream>>>(x, Wg, xbf, eidx);
    convert_we<<<4096, 256, 0, stream>>>(We, webf);
    scatter_kernel<<<256, 256, 0, stream>>>(eidx, tlist, cnts);
    moe_gemm<<<dim3(4, 48, 16), 512, 0, stream>>>(xbf, webf, tlist, cnts, out);
}